// Round 12
// baseline (156.935 us; speedup 1.0000x reference)
//
#include <hip/hip_runtime.h>

#define HW   3136
#define NCH  64
#define CRED 32
#define NB   8
#define EPSV 1e-5f
#define QS2  7

// sqrt(log2(e)) — both theta operands scaled => S' = S * log2(e)
#define SQRT_L2E 1.2011224087f
// log2(log2(e))
#define LOG2_L2E 0.5287663729f

typedef __attribute__((ext_vector_type(8))) short short8;
typedef __attribute__((ext_vector_type(4))) float f32x4;
typedef __attribute__((ext_vector_type(2))) float f32x2;
typedef _Float16 half_t;
typedef __attribute__((ext_vector_type(2))) _Float16 half2v;
typedef __attribute__((ext_vector_type(4))) _Float16 half4v;

#define MFMA_B16 __builtin_amdgcn_mfma_f32_16x16x32_bf16

__device__ __forceinline__ unsigned short f2b(float x) {
    union { float f; unsigned u; } v; v.f = x;
    unsigned r = v.u + 0x7fff + ((v.u >> 16) & 1);
    return (unsigned short)(r >> 16);
}

// raw v_exp_f32: 2^x
__device__ __forceinline__ float ex2(float x) {
#if __has_builtin(__builtin_amdgcn_exp2f)
    return __builtin_amdgcn_exp2f(x);
#else
    float r;
    asm volatile("v_exp_f32 %0, %1" : "=v"(r) : "v"(x));
    return r;
#endif
}

// pack two f32 -> bf16x2 in one instruction
__device__ __forceinline__ unsigned cvtpk(float a, float b) {
    unsigned r;
    asm("v_cvt_pk_bf16_f32 %0, %1, %2" : "=v"(r) : "v"(a), "v"(b));
    return r;
}

// ---- K1: conv1x1 + BN1 + ReLU6 -> Gbt[n][i][p] bf16; theta_bf[n][p][c] scaled --
__global__ __launch_bounds__(256) void k1_conv1x1(
    const float* __restrict__ l, const float* __restrict__ w,
    const float* __restrict__ gamma, const float* __restrict__ beta,
    const float* __restrict__ mean, const float* __restrict__ var,
    unsigned short* __restrict__ theta_bf, unsigned short* __restrict__ Gbt)
{
    __shared__ float Wt[NCH][65];   // Wt[c][i]; reused as G-transpose [i][p]
    __shared__ float Lt[NCH][65];   // Lt[c][j]
    const int t  = threadIdx.x;
    const int n  = blockIdx.y;
    const int p0 = blockIdx.x * 64;

    for (int idx = t; idx < NCH * 64; idx += 256) {
        int c = idx >> 6, j = idx & 63;
        Wt[c][j] = w[j * NCH + c];
        Lt[c][j] = l[((size_t)n * NCH + c) * HW + p0 + j];
    }
    __syncthreads();

    // emit theta_bf[n][p0+p][c0..c0+7], pre-scaled by sqrt(log2 e)
    {
        const int p = t >> 2, c0 = (t & 3) * 8;
        unsigned short pk[8];
#pragma unroll
        for (int j = 0; j < 8; ++j) pk[j] = f2b(Lt[c0 + j][p] * SQRT_L2E);
        *(short8*)&theta_bf[((size_t)n * HW + p0 + p) * CRED + c0] = *(short8*)pk;
    }

    const int i   = t & 63;
    const int pj0 = t >> 6;
    const float mu = mean[i];
    const float sc = rsqrtf(var[i] + EPSV) * gamma[i];
    const float bi = beta[i];

    float acc[16];
#pragma unroll
    for (int k = 0; k < 16; ++k) acc[k] = 0.f;
#pragma unroll
    for (int c = 0; c < NCH; ++c) {
        float wci = Wt[c][i];
#pragma unroll
        for (int k = 0; k < 16; ++k) acc[k] += wci * Lt[c][pj0 + 4 * k];
    }
    __syncthreads();   // all reads of Wt done before reuse

#pragma unroll
    for (int k = 0; k < 16; ++k) {
        float y = (acc[k] - mu) * sc + bi;
        y = fminf(fmaxf(y, 0.f), 6.f);
        Wt[i][pj0 + 4 * k] = y;        // transpose buffer [i][p]
    }
    __syncthreads();

    {
        const int ir = t >> 2, pc = (t & 3) * 16;
        unsigned short pk[16];
#pragma unroll
        for (int j = 0; j < 16; ++j) pk[j] = f2b(Wt[ir][pc + j]);
        unsigned short* dst = &Gbt[((size_t)n * NCH + ir) * HW + p0 + pc];
        *(short8*)&dst[0] = *(short8*)&pk[0];
        *(short8*)&dst[8] = *(short8*)&pk[8];
    }
}

// ---- K2s (MFMA, no LDS): zpart[psp][n][q] = sum_{p in split} 2^(S'[q,p]) -------
__global__ __launch_bounds__(256) void k2s_stats(
    const unsigned short* __restrict__ theta_bf, float* __restrict__ zpart)
{
    const int t = threadIdx.x, w = t >> 6, lane = t & 63;
    const int lo = lane & 15, hi = lane >> 4;
    const int n = blockIdx.z, psp = blockIdx.y;
    const int q0 = blockIdx.x * 64;

    const unsigned short* thn = theta_bf + (size_t)n * HW * CRED;

    const short8 afrag = *(const short8*)&thn[(q0 + w * 16 + lo) * CRED + hi * 8];

    float z[4] = {0.f, 0.f, 0.f, 0.f};

    short8 bf[4];
    {
        const int p0 = psp * 448;
#pragma unroll
        for (int ss = 0; ss < 4; ++ss)
            bf[ss] = *(const short8*)&thn[(p0 + ss * 16 + lo) * CRED + hi * 8];
    }

    for (int pt = 0; pt < 7; ++pt) {
        // prefetch pt+1 fragments (clamped: pt=6 redundantly reloads pt=6, L1-hit)
        const int pn = psp * 448 + ((pt < 6) ? (pt + 1) * 64 : 6 * 64);
        short8 nf[4];
#pragma unroll
        for (int ss = 0; ss < 4; ++ss)
            nf[ss] = *(const short8*)&thn[(pn + ss * 16 + lo) * CRED + hi * 8];

#pragma unroll
        for (int ss = 0; ss < 4; ++ss) {
            f32x4 zero = {0.f, 0.f, 0.f, 0.f};
            f32x4 d = MFMA_B16(afrag, bf[ss], zero, 0, 0, 0);
#pragma unroll
            for (int r = 0; r < 4; ++r) z[r] += ex2(d[r]);
        }

#pragma unroll
        for (int ss = 0; ss < 4; ++ss) bf[ss] = nf[ss];
    }

#pragma unroll
    for (int r = 0; r < 4; ++r) {
        float v = z[r];
        v += __shfl_xor(v, 1, 64);
        v += __shfl_xor(v, 2, 64);
        v += __shfl_xor(v, 4, 64);
        v += __shfl_xor(v, 8, 64);
        z[r] = v;
    }
    if (lo == 0) {
        f32x4 st = {z[0], z[1], z[2], z[3]};
        *(f32x4*)&zpart[((size_t)psp * NB + n) * HW + q0 + w * 16 + hi * 4] = st;
    }
}

// ---- K2c: crow[n][q] = log2(log2 e) - log2(sum_psp zpart) ----------------------
__global__ __launch_bounds__(256) void k2c_combine(
    const float* __restrict__ zpart, float* __restrict__ crow)
{
    const int idx = blockIdx.x * 256 + threadIdx.x;
    float s = 0.f;
#pragma unroll
    for (int ps = 0; ps < QS2; ++ps) s += zpart[(size_t)ps * NB * HW + idx];
    crow[idx] = LOG2_L2E - __log2f(s);
}

// ---- K3f (MFMA): d = S' + crow (C-op); E = 2^(2^d); PV over q-slice ------------
// BARRIER-FREE: the 8 KB G tile is L1/L2-resident (re-read by 4 waves + 49
// neighboring p-blocks), so PV B-fragments load directly from global — no LDS
// staging, no __syncthreads. The only LDS is El, whose rows are wave-private
// (write->read with no barrier: the pattern verified in rounds 6/7/11). All of
// a tile's global loads issue together at tile start and drain under S+ex2.
__global__ __launch_bounds__(256) void k3f_fused(
    const unsigned short* __restrict__ theta_bf,
    const unsigned short* __restrict__ Gbt,
    const float* __restrict__ crow,
    half_t* __restrict__ Part, float* __restrict__ Zpart)
{
    __shared__ unsigned short El[64][76];    // E [p][q] (wave-private rows)

    const int t = threadIdx.x, w = t >> 6, lane = t & 63;
    const int lo = lane & 15, hi = lane >> 4;
    const int n = blockIdx.z, qsp = blockIdx.y;
    const int pblk = blockIdx.x * 64;
    const int pw = w * 16;

    const unsigned short* thn = theta_bf + (size_t)n * HW * CRED;
    const float* crn = crow + (size_t)n * HW;
    const unsigned short* gbn = Gbt + (size_t)n * NCH * HW;

    // block-invariant theta_p fragment
    const short8 bp = *(const short8*)&thn[(pblk + pw + lo) * CRED + hi * 8];

    f32x4 acc[4];
#pragma unroll
    for (int it = 0; it < 4; ++it) acc[it] = (f32x4){0.f, 0.f, 0.f, 0.f};
    float zl = 0.f;

#pragma unroll 1
    for (int tile = 0; tile < 7; ++tile) {
        const int qb = qsp * 448 + tile * 64;

        // ---- issue ALL of this tile's global loads up front
        short8 aqr[4];
        f32x4  cvr[4];
#pragma unroll
        for (int s = 0; s < 4; ++s) {
            aqr[s] = *(const short8*)&thn[(qb + s * 16 + lo) * CRED + hi * 8];
            cvr[s] = *(const f32x4*)&crn[qb + s * 16 + hi * 4];
        }
        short8 bg[8];
#pragma unroll
        for (int ks = 0; ks < 2; ++ks)
#pragma unroll
            for (int it = 0; it < 4; ++it)
                bg[ks * 4 + it] = *(const short8*)
                    &gbn[(size_t)(it * 16 + lo) * HW + qb + ks * 32 + hi * 8];

        // ---- S phase: 4 q-subtiles; E rows -> own-wave El rows
#pragma unroll
        for (int s = 0; s < 4; ++s) {
            f32x4 d = MFMA_B16(aqr[s], bp, cvr[s], 0, 0, 0);
            float e0 = ex2(ex2(d[0]));
            float e1 = ex2(ex2(d[1]));
            float e2 = ex2(ex2(d[2]));
            float e3 = ex2(ex2(d[3]));
            zl += (e0 + e1) + (e2 + e3);
            unsigned* dst = (unsigned*)&El[pw + lo][s * 16 + hi * 4];
            dst[0] = cvtpk(e0, e1);
            dst[1] = cvtpk(e2, e3);
        }

        // ---- PV phase: ae from own El rows (in-order DS per wave), bg from regs
#pragma unroll
        for (int ks = 0; ks < 2; ++ks) {
            const short8 ae = *(const short8*)&El[pw + lo][ks * 32 + hi * 8];
#pragma unroll
            for (int it = 0; it < 4; ++it)
                acc[it] = MFMA_B16(ae, bg[ks * 4 + it], acc[it], 0, 0, 0);
        }
    }

    // Part[n,qsp][i][p] fp16
    half_t* Pn = Part + ((size_t)n * QS2 + qsp) * (size_t)NCH * HW;
#pragma unroll
    for (int it = 0; it < 4; ++it) {
        half4v h;
        h[0] = (half_t)acc[it][0]; h[1] = (half_t)acc[it][1];
        h[2] = (half_t)acc[it][2]; h[3] = (half_t)acc[it][3];
        *(half4v*)&Pn[(size_t)(it * 16 + lo) * HW + pblk + pw + hi * 4] = h;
    }
    zl += __shfl_xor(zl, 16, 64);
    zl += __shfl_xor(zl, 32, 64);
    if (lane < 16)
        Zpart[((size_t)n * QS2 + qsp) * HW + pblk + pw + lane] = zl;
}

// ---- K3r: reduce q-slices (fp16 parts), divide by Z -> OutPre[n][i][p] ---------
__global__ __launch_bounds__(256) void k3r_reduce(
    const half_t* __restrict__ Part, const float* __restrict__ Zpart,
    float* __restrict__ OutPre)
{
    const int t  = threadIdx.x;
    const int p2 = blockIdx.x * 256 + t;       // pair index
    const int i0 = blockIdx.y * 8;
    const int n  = blockIdx.z;
    if (p2 >= HW / 2) return;
    const int p = p2 * 2;

    f32x2 z = {0.f, 0.f};
#pragma unroll
    for (int qs = 0; qs < QS2; ++qs) {
        f32x2 zv = *(const f32x2*)&Zpart[((size_t)n * QS2 + qs) * HW + p];
        z += zv;
    }
    const float zix = 1.f / z[0], ziy = 1.f / z[1];

    float* On = OutPre + (size_t)n * NCH * HW;
#pragma unroll
    for (int j = 0; j < 8; ++j) {
        const int i = i0 + j;
        float sx = 0.f, sy = 0.f;
#pragma unroll
        for (int qs = 0; qs < QS2; ++qs) {
            half2v h = *(const half2v*)&Part[(((size_t)n * QS2 + qs) * NCH + i) * HW + p];
            sx += (float)h[0];
            sy += (float)h[1];
        }
        f32x2 o = {sx * zix, sy * ziy};
        *(f32x2*)&On[(size_t)i * HW + p] = o;
    }
}

// ---- K4: depthwise 3x3 (pad 1) + BN2 + residual -> fp32 out --------------------
__global__ __launch_bounds__(256) void k4_dwconv(
    const float* __restrict__ OutPre, const float* __restrict__ l,
    const float* __restrict__ wdw,
    const float* __restrict__ gamma, const float* __restrict__ beta,
    const float* __restrict__ mean, const float* __restrict__ var,
    float* __restrict__ out)
{
    const size_t e = (size_t)blockIdx.x * 256 + threadIdx.x;
    const int p = (int)(e % HW);
    const int i = (int)((e / HW) % NCH);
    const int y = p / 56, x = p % 56;
    const float* src = OutPre + (e - p);

    float acc = 0.f;
#pragma unroll
    for (int dy = -1; dy <= 1; ++dy) {
        int yy = y + dy;
        if (yy < 0 || yy >= 56) continue;
#pragma unroll
        for (int dx = -1; dx <= 1; ++dx) {
            int xx = x + dx;
            if (xx < 0 || xx >= 56) continue;
            acc += wdw[i * 9 + (dy + 1) * 3 + (dx + 1)] * src[yy * 56 + xx];
        }
    }
    const float sc = rsqrtf(var[i] + EPSV) * gamma[i];
    float yv = (acc - mean[i]) * sc + beta[i];
    yv += l[e];
    out[e] = yv;
}

// -------------------------------------------------------------------------------
extern "C" void kernel_launch(void* const* d_in, const int* in_sizes, int n_in,
                              void* d_out, int out_size, void* d_ws, size_t ws_size,
                              hipStream_t stream)
{
    const float* l      = (const float*)d_in[0];
    const float* w_in   = (const float*)d_in[1];
    const float* gamma1 = (const float*)d_in[2];
    const float* beta1  = (const float*)d_in[3];
    const float* mean1  = (const float*)d_in[4];
    const float* var1   = (const float*)d_in[5];
    const float* w_dw   = (const float*)d_in[6];
    const float* gamma2 = (const float*)d_in[7];
    const float* beta2  = (const float*)d_in[8];
    const float* mean2  = (const float*)d_in[9];
    const float* var2   = (const float*)d_in[10];
    float* out = (float*)d_out;

    char* ws = (char*)d_ws;
    const size_t szTheta = (size_t)NB * HW * CRED * 2;        // 1.6 MB
    const size_t szGbt   = (size_t)NB * NCH * HW * 2;         // 3.2 MB
    const size_t szOut   = (size_t)NB * NCH * HW * 4;         // 6.4 MB
    const size_t szCrow  = (size_t)NB * HW * 4;               // 100 KB
    const size_t szZpt   = (size_t)QS2 * NB * HW * 4;         // 0.7 MB
    const size_t szZp    = (size_t)NB * QS2 * HW * 4;         // 0.7 MB

    unsigned short* theta_bf = (unsigned short*)ws;
    unsigned short* Gbt      = (unsigned short*)(ws + szTheta);
    float* OutPre = (float*)(ws + szTheta + szGbt);
    float* crow   = (float*)(ws + szTheta + szGbt + szOut);
    float* zpart  = (float*)(ws + szTheta + szGbt + szOut + szCrow);
    float* Zp     = (float*)(ws + szTheta + szGbt + szOut + szCrow + szZpt);
    half_t* Part  = (half_t*)(ws + szTheta + szGbt + szOut + szCrow + szZpt + szZp);
    (void)ws_size;

    k1_conv1x1<<<dim3(HW / 64, NB), 256, 0, stream>>>(
        l, w_in, gamma1, beta1, mean1, var1, theta_bf, Gbt);

    k2s_stats<<<dim3(HW / 64, QS2, NB), 256, 0, stream>>>(theta_bf, zpart);

    k2c_combine<<<dim3((NB * HW) / 256), 256, 0, stream>>>(zpart, crow);

    k3f_fused<<<dim3(HW / 64, QS2, NB), 256, 0, stream>>>(
        theta_bf, Gbt, crow, Part, Zp);

    k3r_reduce<<<dim3((HW / 2 + 255) / 256, NCH / 8, NB), 256, 0, stream>>>(
        Part, Zp, OutPre);

    k4_dwconv<<<dim3((NB * NCH * HW) / 256), 256, 0, stream>>>(
        OutPre, l, w_dw, gamma2, beta2, mean2, var2, out);
}

// Round 14
// 104.862 us; speedup vs baseline: 1.4966x; 1.4966x over previous
//
#include <hip/hip_runtime.h>

#define HW   3136
#define NCH  64
#define CRED 32
#define NB   8
#define EPSV 1e-5f
#define QS2  7

// sqrt(log2(e)) — both theta operands scaled => S' = S * log2(e)
#define SQRT_L2E 1.2011224087f
// log2(log2(e))
#define LOG2_L2E 0.5287663729f

typedef __attribute__((ext_vector_type(8))) short short8;
typedef __attribute__((ext_vector_type(4))) float f32x4;
typedef __attribute__((ext_vector_type(2))) float f32x2;
typedef _Float16 half_t;
typedef __attribute__((ext_vector_type(2))) _Float16 half2v;
typedef __attribute__((ext_vector_type(4))) _Float16 half4v;

#define MFMA_B16 __builtin_amdgcn_mfma_f32_16x16x32_bf16

__device__ __forceinline__ unsigned short f2b(float x) {
    union { float f; unsigned u; } v; v.f = x;
    unsigned r = v.u + 0x7fff + ((v.u >> 16) & 1);
    return (unsigned short)(r >> 16);
}

// raw v_exp_f32: 2^x
__device__ __forceinline__ float ex2(float x) {
#if __has_builtin(__builtin_amdgcn_exp2f)
    return __builtin_amdgcn_exp2f(x);
#else
    float r;
    asm volatile("v_exp_f32 %0, %1" : "=v"(r) : "v"(x));
    return r;
#endif
}

// pack two f32 -> bf16x2 in one instruction
__device__ __forceinline__ unsigned cvtpk(float a, float b) {
    unsigned r;
    asm("v_cvt_pk_bf16_f32 %0, %1, %2" : "=v"(r) : "v"(a), "v"(b));
    return r;
}

// ---- K1: conv1x1 + BN1 + ReLU6 -> Gbt[n][i][p] bf16; theta_bf[n][p][c] scaled --
__global__ __launch_bounds__(256) void k1_conv1x1(
    const float* __restrict__ l, const float* __restrict__ w,
    const float* __restrict__ gamma, const float* __restrict__ beta,
    const float* __restrict__ mean, const float* __restrict__ var,
    unsigned short* __restrict__ theta_bf, unsigned short* __restrict__ Gbt)
{
    __shared__ float Wt[NCH][65];   // Wt[c][i]; reused as G-transpose [i][p]
    __shared__ float Lt[NCH][65];   // Lt[c][j]
    const int t  = threadIdx.x;
    const int n  = blockIdx.y;
    const int p0 = blockIdx.x * 64;

    for (int idx = t; idx < NCH * 64; idx += 256) {
        int c = idx >> 6, j = idx & 63;
        Wt[c][j] = w[j * NCH + c];
        Lt[c][j] = l[((size_t)n * NCH + c) * HW + p0 + j];
    }
    __syncthreads();

    // emit theta_bf[n][p0+p][c0..c0+7], pre-scaled by sqrt(log2 e)
    {
        const int p = t >> 2, c0 = (t & 3) * 8;
        unsigned short pk[8];
#pragma unroll
        for (int j = 0; j < 8; ++j) pk[j] = f2b(Lt[c0 + j][p] * SQRT_L2E);
        *(short8*)&theta_bf[((size_t)n * HW + p0 + p) * CRED + c0] = *(short8*)pk;
    }

    const int i   = t & 63;
    const int pj0 = t >> 6;
    const float mu = mean[i];
    const float sc = rsqrtf(var[i] + EPSV) * gamma[i];
    const float bi = beta[i];

    float acc[16];
#pragma unroll
    for (int k = 0; k < 16; ++k) acc[k] = 0.f;
#pragma unroll
    for (int c = 0; c < NCH; ++c) {
        float wci = Wt[c][i];
#pragma unroll
        for (int k = 0; k < 16; ++k) acc[k] += wci * Lt[c][pj0 + 4 * k];
    }
    __syncthreads();   // all reads of Wt done before reuse

#pragma unroll
    for (int k = 0; k < 16; ++k) {
        float y = (acc[k] - mu) * sc + bi;
        y = fminf(fmaxf(y, 0.f), 6.f);
        Wt[i][pj0 + 4 * k] = y;        // transpose buffer [i][p]
    }
    __syncthreads();

    {
        const int ir = t >> 2, pc = (t & 3) * 16;
        unsigned short pk[16];
#pragma unroll
        for (int j = 0; j < 16; ++j) pk[j] = f2b(Wt[ir][pc + j]);
        unsigned short* dst = &Gbt[((size_t)n * NCH + ir) * HW + p0 + pc];
        *(short8*)&dst[0] = *(short8*)&pk[0];
        *(short8*)&dst[8] = *(short8*)&pk[8];
    }
}

// ---- K2s (MFMA, no LDS): zpart[psp][n][q] = sum_{p in split} 2^(S'[q,p]) -------
__global__ __launch_bounds__(256) void k2s_stats(
    const unsigned short* __restrict__ theta_bf, float* __restrict__ zpart)
{
    const int t = threadIdx.x, w = t >> 6, lane = t & 63;
    const int lo = lane & 15, hi = lane >> 4;
    const int n = blockIdx.z, psp = blockIdx.y;
    const int q0 = blockIdx.x * 64;

    const unsigned short* thn = theta_bf + (size_t)n * HW * CRED;

    const short8 afrag = *(const short8*)&thn[(q0 + w * 16 + lo) * CRED + hi * 8];

    float z[4] = {0.f, 0.f, 0.f, 0.f};

    short8 bf[4];
    {
        const int p0 = psp * 448;
#pragma unroll
        for (int ss = 0; ss < 4; ++ss)
            bf[ss] = *(const short8*)&thn[(p0 + ss * 16 + lo) * CRED + hi * 8];
    }

    for (int pt = 0; pt < 7; ++pt) {
        // prefetch pt+1 fragments (clamped: pt=6 redundantly reloads pt=6, L1-hit)
        const int pn = psp * 448 + ((pt < 6) ? (pt + 1) * 64 : 6 * 64);
        short8 nf[4];
#pragma unroll
        for (int ss = 0; ss < 4; ++ss)
            nf[ss] = *(const short8*)&thn[(pn + ss * 16 + lo) * CRED + hi * 8];

#pragma unroll
        for (int ss = 0; ss < 4; ++ss) {
            f32x4 zero = {0.f, 0.f, 0.f, 0.f};
            f32x4 d = MFMA_B16(afrag, bf[ss], zero, 0, 0, 0);
#pragma unroll
            for (int r = 0; r < 4; ++r) z[r] += ex2(d[r]);
        }

#pragma unroll
        for (int ss = 0; ss < 4; ++ss) bf[ss] = nf[ss];
    }

#pragma unroll
    for (int r = 0; r < 4; ++r) {
        float v = z[r];
        v += __shfl_xor(v, 1, 64);
        v += __shfl_xor(v, 2, 64);
        v += __shfl_xor(v, 4, 64);
        v += __shfl_xor(v, 8, 64);
        z[r] = v;
    }
    if (lo == 0) {
        f32x4 st = {z[0], z[1], z[2], z[3]};
        *(f32x4*)&zpart[((size_t)psp * NB + n) * HW + q0 + w * 16 + hi * 4] = st;
    }
}

// ---- K2c: crow[n][q] = log2(log2 e) - log2(sum_psp zpart) ----------------------
__global__ __launch_bounds__(256) void k2c_combine(
    const float* __restrict__ zpart, float* __restrict__ crow)
{
    const int idx = blockIdx.x * 256 + threadIdx.x;
    float s = 0.f;
#pragma unroll
    for (int ps = 0; ps < QS2; ++ps) s += zpart[(size_t)ps * NB * HW + idx];
    crow[idx] = LOG2_L2E - __log2f(s);
}

// ---- K3f (MFMA): d = S' + crow (C-op); E = 2^(2^d); PV over q-slice ------------
// EXACT r10/r11-verified kernel (passed twice, 48.5 us): 2 barriers/tile, single
// Glt buffer, aq/crow loads issued in the staging region so they drain at the
// barrier's implicit vmcnt(0); El write->read wave-private with no barrier.
__global__ __launch_bounds__(256) void k3f_fused(
    const unsigned short* __restrict__ theta_bf,
    const unsigned short* __restrict__ Gbt,
    const float* __restrict__ crow,
    half_t* __restrict__ Part, float* __restrict__ Zpart)
{
    __shared__ unsigned short Glt[64][76];   // G^T [i][q], pad 76
    __shared__ unsigned short El[64][76];    // E   [p][q] (wave-private rows)

    const int t = threadIdx.x, w = t >> 6, lane = t & 63;
    const int lo = lane & 15, hi = lane >> 4;
    const int n = blockIdx.z, qsp = blockIdx.y;
    const int pblk = blockIdx.x * 64;
    const int pw = w * 16;

    const unsigned short* thn = theta_bf + (size_t)n * HW * CRED;
    const float* crn = crow + (size_t)n * HW;

    // block-invariant theta_p fragment, direct from global
    const short8 bp = *(const short8*)&thn[(pblk + pw + lo) * CRED + hi * 8];

    f32x4 acc[4];
#pragma unroll
    for (int it = 0; it < 4; ++it) acc[it] = (f32x4){0.f, 0.f, 0.f, 0.f};
    float zl = 0.f;

    for (int tile = 0; tile < 7; ++tile) {
        const int qb = qsp * 448 + tile * 64;
        __syncthreads();
        // stage G^T tile: pure bf16 row copy
        {
            const int ir = t >> 2, qoff = (t & 3) * 16;
            const unsigned short* src = &Gbt[((size_t)n * NCH + ir) * HW + qb + qoff];
            *(short8*)&Glt[ir][qoff]     = *(const short8*)&src[0];
            *(short8*)&Glt[ir][qoff + 8] = *(const short8*)&src[8];
        }
        // issue this tile's aq/crow loads here: they complete by the barrier's
        // implicit vmcnt(0) drain, making the S phase pure compute.
        short8 aqr[4];
        f32x4  cvr[4];
#pragma unroll
        for (int s = 0; s < 4; ++s) {
            aqr[s] = *(const short8*)&thn[(qb + s * 16 + lo) * CRED + hi * 8];
            cvr[s] = *(const f32x4*)&crn[qb + s * 16 + hi * 4];
        }
        __syncthreads();

        // S phase: 4 q-subtiles; E rows -> El[p][q]
#pragma unroll
        for (int s = 0; s < 4; ++s) {
            f32x4 d = MFMA_B16(aqr[s], bp, cvr[s], 0, 0, 0);
            float e0 = ex2(ex2(d[0]));
            float e1 = ex2(ex2(d[1]));
            float e2 = ex2(ex2(d[2]));
            float e3 = ex2(ex2(d[3]));
            zl += (e0 + e1) + (e2 + e3);
            unsigned* dst = (unsigned*)&El[pw + lo][s * 16 + hi * 4];
            dst[0] = cvtpk(e0, e1);
            dst[1] = cvtpk(e2, e3);
        }

        // PV phase: acc[it] (D[p][i]) += El[p][q] * Glt[i][q]
#pragma unroll
        for (int ks = 0; ks < 2; ++ks) {
            const short8 ae = *(const short8*)&El[pw + lo][ks * 32 + hi * 8];
#pragma unroll
            for (int it = 0; it < 4; ++it) {
                const short8 bg = *(const short8*)&Glt[it * 16 + lo][ks * 32 + hi * 8];
                acc[it] = MFMA_B16(ae, bg, acc[it], 0, 0, 0);
            }
        }
    }

    // Part[n,qsp][i][p] fp16
    half_t* Pn = Part + ((size_t)n * QS2 + qsp) * (size_t)NCH * HW;
#pragma unroll
    for (int it = 0; it < 4; ++it) {
        half4v h;
        h[0] = (half_t)acc[it][0]; h[1] = (half_t)acc[it][1];
        h[2] = (half_t)acc[it][2]; h[3] = (half_t)acc[it][3];
        *(half4v*)&Pn[(size_t)(it * 16 + lo) * HW + pblk + pw + hi * 4] = h;
    }
    zl += __shfl_xor(zl, 16, 64);
    zl += __shfl_xor(zl, 32, 64);
    if (lane < 16)
        Zpart[((size_t)n * QS2 + qsp) * HW + pblk + pw + lane] = zl;
}

// ---- K34: fused (reduce q-slices + Z-normalize) + depthwise 3x3 + BN2 + res ----
// block: (band of 14 y-rows, 4 channels, batch n). Reduces Part for the 16-row
// halo band into LDS, then applies the stencil + BN2 + residual directly.
__global__ __launch_bounds__(256) void k34_reduce_dw(
    const half_t* __restrict__ Part, const float* __restrict__ Zpart,
    const float* __restrict__ l, const float* __restrict__ wdw,
    const float* __restrict__ gamma, const float* __restrict__ beta,
    const float* __restrict__ mean, const float* __restrict__ var,
    float* __restrict__ out)
{
    __shared__ float op[4][16][56];   // normalized OutPre, halo rows
    __shared__ float zsh[16 * 56];    // 1/Z for halo rows
    __shared__ float wsh[36];         // dw weights for the 4 channels

    const int t    = threadIdx.x;
    const int band = blockIdx.x;            // 0..3, y0 = band*14
    const int i0   = blockIdx.y * 4;        // channel group
    const int n    = blockIdx.z;
    const int y0   = band * 14;

    if (t < 36) wsh[t] = wdw[i0 * 9 + t];

    // 1/Z for halo rows [y0-1, y0+14]
    for (int idx = t; idx < 16 * 56; idx += 256) {
        const int yy = y0 - 1 + idx / 56, x = idx % 56;
        if (yy >= 0 && yy < 56) {
            const int p = yy * 56 + x;
            float z = 0.f;
#pragma unroll
            for (int qs = 0; qs < QS2; ++qs)
                z += Zpart[((size_t)n * QS2 + qs) * HW + p];
            zsh[idx] = 1.f / z;
        }
    }
    __syncthreads();

    // reduce Part over 7 slices, normalize -> op[c][row][x]
    for (int idx = t; idx < 4 * 16 * 56; idx += 256) {
        const int c = idx / (16 * 56), rem = idx % (16 * 56);
        const int yy = y0 - 1 + rem / 56, x = rem % 56;
        if (yy >= 0 && yy < 56) {
            const int p = yy * 56 + x;
            const int i = i0 + c;
            float s = 0.f;
#pragma unroll
            for (int qs = 0; qs < QS2; ++qs)
                s += (float)Part[(((size_t)n * QS2 + qs) * NCH + i) * HW + p];
            op[c][rem / 56][x] = s * zsh[rem];
        }
    }
    __syncthreads();

    // stencil + BN2 + residual for y in [y0, y0+13]
    for (int idx = t; idx < 4 * 14 * 56; idx += 256) {
        const int c = idx / (14 * 56), rem = idx % (14 * 56);
        const int y = y0 + rem / 56, x = rem % 56;
        const int i = i0 + c;

        float acc = 0.f;
#pragma unroll
        for (int dy = -1; dy <= 1; ++dy) {
            const int yy = y + dy;
            if (yy < 0 || yy >= 56) continue;
            const int ly = yy - (y0 - 1);
#pragma unroll
            for (int dx = -1; dx <= 1; ++dx) {
                const int xx = x + dx;
                if (xx < 0 || xx >= 56) continue;
                acc += wsh[c * 9 + (dy + 1) * 3 + (dx + 1)] * op[c][ly][xx];
            }
        }
        const float sc = rsqrtf(var[i] + EPSV) * gamma[i];
        const size_t e = ((size_t)n * NCH + i) * HW + y * 56 + x;
        out[e] = (acc - mean[i]) * sc + beta[i] + l[e];
    }
}

// -------------------------------------------------------------------------------
extern "C" void kernel_launch(void* const* d_in, const int* in_sizes, int n_in,
                              void* d_out, int out_size, void* d_ws, size_t ws_size,
                              hipStream_t stream)
{
    const float* l      = (const float*)d_in[0];
    const float* w_in   = (const float*)d_in[1];
    const float* gamma1 = (const float*)d_in[2];
    const float* beta1  = (const float*)d_in[3];
    const float* mean1  = (const float*)d_in[4];
    const float* var1   = (const float*)d_in[5];
    const float* w_dw   = (const float*)d_in[6];
    const float* gamma2 = (const float*)d_in[7];
    const float* beta2  = (const float*)d_in[8];
    const float* mean2  = (const float*)d_in[9];
    const float* var2   = (const float*)d_in[10];
    float* out = (float*)d_out;

    char* ws = (char*)d_ws;
    const size_t szTheta = (size_t)NB * HW * CRED * 2;        // 1.6 MB
    const size_t szGbt   = (size_t)NB * NCH * HW * 2;         // 3.2 MB
    const size_t szCrow  = (size_t)NB * HW * 4;               // 100 KB
    const size_t szZpt   = (size_t)QS2 * NB * HW * 4;         // 0.7 MB
    const size_t szZp    = (size_t)NB * QS2 * HW * 4;         // 0.7 MB

    unsigned short* theta_bf = (unsigned short*)ws;
    unsigned short* Gbt      = (unsigned short*)(ws + szTheta);
    float* crow   = (float*)(ws + szTheta + szGbt);
    float* zpart  = (float*)(ws + szTheta + szGbt + szCrow);
    float* Zp     = (float*)(ws + szTheta + szGbt + szCrow + szZpt);
    half_t* Part  = (half_t*)(ws + szTheta + szGbt + szCrow + szZpt + szZp);
    (void)ws_size;

    k1_conv1x1<<<dim3(HW / 64, NB), 256, 0, stream>>>(
        l, w_in, gamma1, beta1, mean1, var1, theta_bf, Gbt);

    k2s_stats<<<dim3(HW / 64, QS2, NB), 256, 0, stream>>>(theta_bf, zpart);

    k2c_combine<<<dim3((NB * HW) / 256), 256, 0, stream>>>(zpart, crow);

    k3f_fused<<<dim3(HW / 64, QS2, NB), 256, 0, stream>>>(
        theta_bf, Gbt, crow, Part, Zp);

    k34_reduce_dw<<<dim3(4, NCH / 4, NB), 256, 0, stream>>>(
        Part, Zp, l, w_dw, gamma2, beta2, mean2, var2, out);
}